// Round 1
// 384.172 us; speedup vs baseline: 1.0804x; 1.0804x over previous
//
#include <hip/hip_runtime.h>

// MultiHeadAttention: B=4, S=2048, D=1024, H=16, DH=64
// out = ((softmax(mask(QK^T/8)) V) merged) @ Wo^T
// bf16 MFMA, f32 accum. No-max softmax (Q pre-scaled by 0.125*log2e).
// Attention computes S^T (A=K, B=Q). Key rows are PERMUTED in LDS
// (p = 32kk+8q+4h+r stored at row 32kk+16h+4q+r) so that the S^T output of an
// mt-pair lands in-register in exact K=32 A-fragment layout -> PV runs at full
// mfma_f32_16x16x32 rate with zero cross-lane shuffles. K/V staged via
// global_load_lds with 16B XOR swizzle (pre-swizzled global source, linear LDS
// dest) -> conflict-free ds_read_b128. Mask folded into V^T columns and a
// ones-vector fmb (staged once for all 2048 keys).

#define BB 4
#define SS 2048
#define DD 1024
#define HH 16
#define DH 64

typedef __bf16 bf16x8 __attribute__((ext_vector_type(8)));
typedef float floatx4 __attribute__((ext_vector_type(4)));
typedef unsigned short ushortx8 __attribute__((ext_vector_type(8)));
typedef unsigned short ushortx4 __attribute__((ext_vector_type(4)));
typedef unsigned short ushort_t;

__device__ __forceinline__ unsigned short f2bf(float f) {
    unsigned u = __builtin_bit_cast(unsigned, f);
    u += 0x7FFFu + ((u >> 16) & 1u);   // RNE
    return (unsigned short)(u >> 16);
}

__device__ __forceinline__ bf16x8 ldb(const ushort_t* p) {
    return __builtin_bit_cast(bf16x8, *(const ushortx8*)p);
}

// async global->LDS, 16B per lane; lds dest must be wave-uniform base + lane*16
__device__ __forceinline__ void dma16(const ushort_t* g, ushort_t* l) {
    __builtin_amdgcn_global_load_lds(
        (const __attribute__((address_space(1))) unsigned int*)g,
        (__attribute__((address_space(3))) unsigned int*)l, 16, 0, 0);
}

__device__ __forceinline__ floatx4 mfma32(bf16x8 a, bf16x8 b, floatx4 c) {
    return __builtin_amdgcn_mfma_f32_16x16x32_bf16(a, b, c, 0, 0, 0);
}

__device__ __forceinline__ floatx4 fzero() {
    floatx4 z = {0.f, 0.f, 0.f, 0.f};
    return z;
}

// ---------------- f32 -> bf16 convert ----------------
__global__ void cvt_f32_bf16(const float* __restrict__ in, ushort_t* __restrict__ out, int n) {
    int i = (blockIdx.x * blockDim.x + threadIdx.x) * 4;
    if (i < n) {
        float4 f = *(const float4*)&in[i];
        ushortx4 o;
        o[0] = f2bf(f.x); o[1] = f2bf(f.y); o[2] = f2bf(f.z); o[3] = f2bf(f.w);
        *(ushortx4*)&out[i] = o;
    }
}

// ---------------- GEMM core: acc[m][n] = sum_k A[m,k] * B[n,k], 128x128 tile ----------------
__device__ __forceinline__ void gemm_core(
    const ushort_t* __restrict__ Ab, const ushort_t* __restrict__ Bb,
    floatx4 acc[4][4], ushort_t (*As)[32], ushort_t (*Bs)[32], int tid)
{
    const int wv = tid >> 6, lane = tid & 63;
    const int quad = lane >> 4, lid = lane & 15;
    const int wm = wv & 1, wn = wv >> 1;
    const int r0 = lane >> 2, c0 = (lane & 3) * 8;

#pragma unroll
    for (int i = 0; i < 4; ++i)
#pragma unroll
        for (int j = 0; j < 4; ++j) acc[i][j] = fzero();

    for (int k0 = 0; k0 < DD; k0 += 32) {
        __syncthreads();
#pragma unroll
        for (int s = 0; s < 2; ++s) {
            int seg = wv * 2 + s;
            dma16(&Ab[(size_t)(seg * 16 + r0) * DD + k0 + c0], &As[seg * 16][0]);
            dma16(&Bb[(size_t)(seg * 16 + r0) * DD + k0 + c0], &Bs[seg * 16][0]);
        }
        __syncthreads();

        bf16x8 af[4], bfr[4];
#pragma unroll
        for (int mt = 0; mt < 4; ++mt) af[mt] = ldb(&As[wm * 64 + mt * 16 + lid][quad * 8]);
#pragma unroll
        for (int nt = 0; nt < 4; ++nt) bfr[nt] = ldb(&Bs[wn * 64 + nt * 16 + lid][quad * 8]);
#pragma unroll
        for (int mt = 0; mt < 4; ++mt)
#pragma unroll
            for (int nt = 0; nt < 4; ++nt)
                acc[mt][nt] = mfma32(af[mt], bfr[nt], acc[mt][nt]);
    }
}

// ---------------- fused QKV projection ----------------
// grid (24, 64): bx>>3 selects {query,key,value}. Q: (B,H,S,DH) pre-scaled by
// 0.125*log2e. K: (B,H,S,DH). V: (B,H,DH,S) = V^T with mask folded in (masked
// key s -> 0). Epilogues: per-wave LDS transpose -> 16B coalesced stores.
__global__ __launch_bounds__(256) void gemm_qkv(
    const ushort_t* __restrict__ Qa, const ushort_t* __restrict__ Ka,
    const ushort_t* __restrict__ Va, const ushort_t* __restrict__ Wqkv,
    const int* __restrict__ maskg,
    ushort_t* __restrict__ Qp, ushort_t* __restrict__ Kp, ushort_t* __restrict__ Vtp)
{
    __shared__ ushort_t As[128][32];
    __shared__ ushort_t Bs[128][32];
    __shared__ ushort_t Ts[4][16][72];   // per-wave epilogue transpose buffer

    const int tid = threadIdx.x;
    const int which = blockIdx.x >> 3;
    const int m0 = blockIdx.y * 128;
    const int n0 = blockIdx.x * 128;
    const ushort_t* Ab = (which == 0 ? Qa : which == 1 ? Ka : Va) + (size_t)m0 * DD;
    const ushort_t* Bb = Wqkv + (size_t)n0 * DD;

    floatx4 acc[4][4];
    gemm_core(Ab, Bb, acc, As, Bs, tid);

    const int wv = tid >> 6, lane = tid & 63;
    const int quad = lane >> 4, lid = lane & 15;
    const int wm = wv & 1, wn = wv >> 1;
    const int b = m0 >> 11;                 // batch uniform per block
    const int sbase = (m0 & 2047) + wm * 64;
    const int nl0 = n0 - which * 1024 + wn * 64;   // local n base of this wave
    const int sl = lane >> 2, cl = (lane & 3) * 16;

    if (which == 2) {
        // V^T: (B,H,DH,S), masked. Per nt: pack 4 s-consecutive vals -> b64 LDS,
        // read back dh-rows of 16 s-contiguous -> dwordx4 stores.
        const int* maskb = maskg + b * SS;
#pragma unroll
        for (int nt = 0; nt < 4; ++nt) {
#pragma unroll
            for (int mt = 0; mt < 4; ++mt) {
                int sp = sbase + mt * 16 + quad * 4;
                int4 mv = *(const int4*)&maskb[sp];
                ushortx4 o;
                o[0] = mv.x ? (ushort_t)0 : f2bf(acc[mt][nt][0]);
                o[1] = mv.y ? (ushort_t)0 : f2bf(acc[mt][nt][1]);
                o[2] = mv.z ? (ushort_t)0 : f2bf(acc[mt][nt][2]);
                o[3] = mv.w ? (ushort_t)0 : f2bf(acc[mt][nt][3]);
                *(ushortx4*)&Ts[wv][lid][mt * 16 + quad * 4] = o;
            }
            ushortx8 w0 = *(const ushortx8*)&Ts[wv][sl][cl];
            ushortx8 w1 = *(const ushortx8*)&Ts[wv][sl][cl + 8];
            int nl = nl0 + nt * 16 + sl;
            int h = nl >> 6, dh = nl & 63;
            size_t base = (((size_t)b * HH + h) * DH + dh) * SS + sbase + cl;
            *(ushortx8*)&Vtp[base] = w0;
            *(ushortx8*)&Vtp[base + 8] = w1;
        }
    } else {
        // Q/K: (B,H,S,DH). Per mt: scatter 16 b16 into LDS s-major tile, read
        // back s-rows of 16 dh-contiguous -> dwordx4 stores.
        ushort_t* P = which ? Kp : Qp;
        const float scl = which ? 1.0f : 0.125f * 1.4426950408889634f;
        const int h = nl0 >> 6;
#pragma unroll
        for (int mt = 0; mt < 4; ++mt) {
#pragma unroll
            for (int nt = 0; nt < 4; ++nt)
#pragma unroll
                for (int r = 0; r < 4; ++r)
                    Ts[wv][quad * 4 + r][nt * 16 + lid] = f2bf(acc[mt][nt][r] * scl);
            ushortx8 w0 = *(const ushortx8*)&Ts[wv][sl][cl];
            ushortx8 w1 = *(const ushortx8*)&Ts[wv][sl][cl + 8];
            int s = sbase + mt * 16 + sl;
            size_t base = (((size_t)b * HH + h) * SS + s) * DH + (nl0 & 63) + cl;
            *(ushortx8*)&P[base] = w0;
            *(ushortx8*)&P[base + 8] = w1;
        }
    }
}

// ---------------- final projection: out = Cx @ Wo^T, f32 out ----------------
__global__ __launch_bounds__(256) void gemm_o(
    const ushort_t* __restrict__ Cx, const ushort_t* __restrict__ Wo,
    float* __restrict__ Out)
{
    __shared__ ushort_t As[128][32];
    __shared__ ushort_t Bs[128][32];
    const int tid = threadIdx.x;
    const int m0 = blockIdx.y * 128;
    const int n0 = blockIdx.x * 128;

    floatx4 acc[4][4];
    gemm_core(Cx + (size_t)m0 * DD, Wo + (size_t)n0 * DD, acc, As, Bs, tid);

    const int wv = tid >> 6, lane = tid & 63;
    const int quad = lane >> 4, lid = lane & 15;
    const int wm = wv & 1, wn = wv >> 1;
#pragma unroll
    for (int mt = 0; mt < 4; ++mt)
#pragma unroll
        for (int nt = 0; nt < 4; ++nt)
#pragma unroll
            for (int r = 0; r < 4; ++r) {
                int m = m0 + wm * 64 + mt * 16 + quad * 4 + r;
                int n = n0 + wn * 64 + nt * 16 + lid;
                Out[(size_t)m * DD + n] = acc[mt][nt][r];
            }
}

// ---------------- flash attention (S^T scheme, K=32 PV via key-row permute) ----
// flat grid 2048, XCD swizzle: xcd=id&7 owns 8 bh (K/V L2-resident).
// Per wave: 16 queries (q=lid). S^T = K·Q^T with key rows permuted in LDS:
// physical key p = 32kk+8quad+4h+r stored at row 32kk+16h+4quad+r. After the
// S^T MFMAs for mt-pair (2kk,2kk+1), lane (quad,lid) holds P[q=lid] for
// physical keys kk*32+quad*8+{0..7} == the exact K=32 A-fragment -> PV and the
// denominator (ones-vector fmb) run as full-rate mfma32. K/V staged by
// global_load_lds (linear LDS dest, 16B-XOR pre-swizzled global source);
// reads XOR the same (row&7)<<3 -> conflict-free ds_read_b128.
__global__ __launch_bounds__(256) void attn_kernel(
    const ushort_t* __restrict__ Qg, const ushort_t* __restrict__ Kg,
    const ushort_t* __restrict__ Vtg, const int* __restrict__ maskg,
    ushort_t* __restrict__ Ctx)
{
    __shared__ ushort_t Ks[64 * 64];    // [perm key row][dh ^ swz]  8 KB
    __shared__ ushort_t Vts[64 * 64];   // [dh][key ^ swz] (pre-masked) 8 KB
    __shared__ ushort_t fmb[SS];        // bf16 1.0/0.0 per key, all 2048  4 KB

    const int flat = blockIdx.x;
    const int xcd = flat & 7;
    const int slot = flat >> 3;
    const int bh = xcd * 8 + (slot >> 5);
    const int qc = slot & 31;
    const int b = bh >> 4, h = bh & 15;
    const int tid = threadIdx.x;
    const int wv = tid >> 6, lane = tid & 63;
    const int quad = lane >> 4, lid = lane & 15;

    const ushort_t* Qb = Qg + (size_t)bh * SS * DH;
    const ushort_t* Kb = Kg + (size_t)bh * SS * DH;
    const ushort_t* Vtb = Vtg + (size_t)bh * DH * SS;
    const int* maskb = maskg + b * SS;

    // ones-vector for all 2048 keys, staged once (8 keys/thread)
    {
        const int k8 = tid * 8;
        int4 ma = *(const int4*)&maskb[k8];
        int4 mb2 = *(const int4*)&maskb[k8 + 4];
        ushortx8 f;
        f[0] = ma.x ? (ushort_t)0 : (ushort_t)0x3F80;
        f[1] = ma.y ? (ushort_t)0 : (ushort_t)0x3F80;
        f[2] = ma.z ? (ushort_t)0 : (ushort_t)0x3F80;
        f[3] = ma.w ? (ushort_t)0 : (ushort_t)0x3F80;
        f[4] = mb2.x ? (ushort_t)0 : (ushort_t)0x3F80;
        f[5] = mb2.y ? (ushort_t)0 : (ushort_t)0x3F80;
        f[6] = mb2.z ? (ushort_t)0 : (ushort_t)0x3F80;
        f[7] = mb2.w ? (ushort_t)0 : (ushort_t)0x3F80;
        *(ushortx8*)&fmb[k8] = f;
    }

    const int q0 = qc * 64 + wv * 16;

    bf16x8 qf0, qf1;   // B-operand: n=lid -> query q0+lid, k=dh
    {
        const int row = q0 + lid;
        qf0 = ldb(&Qb[(size_t)row * DH + quad * 8]);
        qf1 = ldb(&Qb[(size_t)row * DH + 32 + quad * 8]);
    }

    // per-lane staging source offsets (elements), computed once.
    // lane covers LDS 16B chunk idx = wv*128 + s*64 + lane: ldsrow=idx>>3,
    // chunk c16=idx&7. K source row = perm(ldsrow); col chunk = c16 ^ (row&7).
    int offK[2], offV[2];
#pragma unroll
    for (int s = 0; s < 2; ++s) {
        int idx = wv * 128 + s * 64 + lane;
        int row = idx >> 3;
        int c16 = idx & 7;
        // perm: row bits [kk h quad r] -> p bits [kk quad h r]
        int p = (row & 35) | ((row & 12) << 1) | ((row & 16) >> 2);
        int colu = (c16 ^ (row & 7)) << 3;
        offK[s] = p * DH + colu;
        offV[s] = row * SS + colu;
    }

    floatx4 Oacc[4];
    floatx4 Osum = fzero();
#pragma unroll
    for (int i = 0; i < 4; ++i) Oacc[i] = fzero();

    const ushort_t* Kc = Kb;
    const ushort_t* Vc = Vtb;
    const int swz = (lid & 7) << 3;

    for (int kc = 0; kc < SS / 64; ++kc) {
        __syncthreads();
        dma16(Kc + offK[0], &Ks[(wv * 2 + 0) * 512]);
        dma16(Kc + offK[1], &Ks[(wv * 2 + 1) * 512]);
        dma16(Vc + offV[0], &Vts[(wv * 2 + 0) * 512]);
        dma16(Vc + offV[1], &Vts[(wv * 2 + 1) * 512]);
        __syncthreads();

        // S^T = K·Q^T on permuted key rows: lane (quad,lid) gets q=lid and
        // LDS rows mt*16+quad*4+r  ==  physical keys (mt>>1)*32+quad*8+4*(mt&1)+r
        floatx4 st[4];
#pragma unroll
        for (int mt = 0; mt < 4; ++mt) {
            const int rb = (mt * 16 + lid) * 64;
            bf16x8 kf0 = ldb(&Ks[rb + ((quad * 8) ^ swz)]);
            bf16x8 kf1 = ldb(&Ks[rb + ((32 + quad * 8) ^ swz)]);
            st[mt] = mfma32(kf1, qf1, mfma32(kf0, qf0, fzero()));
        }

        // per 32-key block: exp2 in place -> full K=32 A-fragment, PV + denom
#pragma unroll
        for (int kk = 0; kk < 2; ++kk) {
            bf16x8 pa;
#pragma unroll
            for (int r = 0; r < 4; ++r) {
                pa[r]     = (__bf16)__builtin_amdgcn_exp2f(st[2 * kk][r]);
                pa[r + 4] = (__bf16)__builtin_amdgcn_exp2f(st[2 * kk + 1][r]);
            }
            bf16x8 fm = ldb(&fmb[kc * 64 + kk * 32 + quad * 8]);
            Osum = mfma32(pa, fm, Osum);
#pragma unroll
            for (int nt = 0; nt < 4; ++nt) {
                bf16x8 vb = ldb(&Vts[(nt * 16 + lid) * 64 + ((kk * 32 + quad * 8) ^ swz)]);
                Oacc[nt] = mfma32(pa, vb, Oacc[nt]);
            }
        }

        Kc += 64 * DH;
        Vc += 64;
    }

    // Osum[r] = row sum for q = q0+quad*4+r (identical in every column/lane-lid)
    float inv[4];
#pragma unroll
    for (int r = 0; r < 4; ++r) inv[r] = 1.0f / Osum[r];

#pragma unroll
    for (int nt = 0; nt < 4; ++nt) {
#pragma unroll
        for (int r = 0; r < 4; ++r) {
            int s = q0 + quad * 4 + r;
            int dh = nt * 16 + lid;
            Ctx[(((size_t)b * SS + s) * HH + h) * DH + dh] = f2bf(Oacc[nt][r] * inv[r]);
        }
    }
}

// ---------------- launch ----------------
extern "C" void kernel_launch(void* const* d_in, const int* in_sizes, int n_in,
                              void* d_out, int out_size, void* d_ws, size_t ws_size,
                              hipStream_t stream) {
    const float* q  = (const float*)d_in[0];
    const float* k  = (const float*)d_in[1];
    const float* v  = (const float*)d_in[2];
    const int*   mask = (const int*)d_in[3];
    const float* Wq = (const float*)d_in[4];
    const float* Wk = (const float*)d_in[5];
    const float* Wv = (const float*)d_in[6];
    const float* Wo = (const float*)d_in[7];
    float* out = (float*)d_out;

    char* ws = (char*)d_ws;
    const size_t MB = 1024 * 1024;
    ushort_t* Qin  = (ushort_t*)(ws + 0 * MB);    // 16 MB each
    ushort_t* Kin  = (ushort_t*)(ws + 16 * MB);
    ushort_t* Vin  = (ushort_t*)(ws + 32 * MB);
    ushort_t* Qp   = (ushort_t*)(ws + 48 * MB);
    ushort_t* Kp   = (ushort_t*)(ws + 64 * MB);
    ushort_t* Vtp  = (ushort_t*)(ws + 80 * MB);
    ushort_t* Wqkv = (ushort_t*)(ws + 96 * MB);   // 6 MB
    ushort_t* Wob  = (ushort_t*)(ws + 102 * MB);  // 2 MB
    ushort_t* Cx   = Qin;                         // Qin dead after gemm_qkv

    const int INEL = BB * SS * DD;   // 8.4M
    const int WN = DD * DD;          // 1M
    cvt_f32_bf16<<<INEL / 1024, 256, 0, stream>>>(q, Qin, INEL);
    cvt_f32_bf16<<<INEL / 1024, 256, 0, stream>>>(k, Kin, INEL);
    cvt_f32_bf16<<<INEL / 1024, 256, 0, stream>>>(v, Vin, INEL);
    cvt_f32_bf16<<<WN / 1024, 256, 0, stream>>>(Wq, Wqkv, WN);
    cvt_f32_bf16<<<WN / 1024, 256, 0, stream>>>(Wk, Wqkv + WN, WN);
    cvt_f32_bf16<<<WN / 1024, 256, 0, stream>>>(Wv, Wqkv + 2 * WN, WN);
    cvt_f32_bf16<<<WN / 1024, 256, 0, stream>>>(Wo, Wob, WN);

    gemm_qkv<<<dim3(24, 64), 256, 0, stream>>>(Qin, Kin, Vin, Wqkv, mask, Qp, Kp, Vtp);
    attn_kernel<<<dim3(2048), 256, 0, stream>>>(Qp, Kp, Vtp, mask, Cx);
    gemm_o<<<dim3(8, 64), 256, 0, stream>>>(Cx, Wob, out);
}

// Round 2
// 344.516 us; speedup vs baseline: 1.2047x; 1.1151x over previous
//
#include <hip/hip_runtime.h>

// MultiHeadAttention: B=4, S=2048, D=1024, H=16, DH=64
// out = ((softmax(mask(QK^T/8)) V) merged) @ Wo^T
// bf16 MFMA, f32 accum. No-max softmax (Q pre-scaled by 0.125*log2e).
// This round: (1) gemm_core + attn converted to 2-phase double-buffered LDS
// (issue next-tile global_load_lds BEFORE computing current tile; one
// __syncthreads per K-step) -> hides HBM latency under MFMA. (2) bijective
// XCD swizzle on both GEMM grids so blocks sharing an A-slice co-reside on
// one XCD's L2. (3) cvt dispatches merged 7 -> 2.

#define BB 4
#define SS 2048
#define DD 1024
#define HH 16
#define DH 64

typedef __bf16 bf16x8 __attribute__((ext_vector_type(8)));
typedef float floatx4 __attribute__((ext_vector_type(4)));
typedef unsigned short ushortx8 __attribute__((ext_vector_type(8)));
typedef unsigned short ushortx4 __attribute__((ext_vector_type(4)));
typedef unsigned short ushort_t;

__device__ __forceinline__ unsigned short f2bf(float f) {
    unsigned u = __builtin_bit_cast(unsigned, f);
    u += 0x7FFFu + ((u >> 16) & 1u);   // RNE
    return (unsigned short)(u >> 16);
}

__device__ __forceinline__ bf16x8 ldb(const ushort_t* p) {
    return __builtin_bit_cast(bf16x8, *(const ushortx8*)p);
}

// async global->LDS, 16B per lane; lds dest must be wave-uniform base + lane*16
__device__ __forceinline__ void dma16(const ushort_t* g, ushort_t* l) {
    __builtin_amdgcn_global_load_lds(
        (const __attribute__((address_space(1))) unsigned int*)g,
        (__attribute__((address_space(3))) unsigned int*)l, 16, 0, 0);
}

__device__ __forceinline__ floatx4 mfma32(bf16x8 a, bf16x8 b, floatx4 c) {
    return __builtin_amdgcn_mfma_f32_16x16x32_bf16(a, b, c, 0, 0, 0);
}

__device__ __forceinline__ floatx4 fzero() {
    floatx4 z = {0.f, 0.f, 0.f, 0.f};
    return z;
}

// ---------------- f32 -> bf16 converts (merged dispatches) ----------------
__device__ __forceinline__ void cvt_body(const float* __restrict__ in,
                                         ushort_t* __restrict__ out) {
    int i = (blockIdx.x * blockDim.x + threadIdx.x) * 4;
    float4 f = *(const float4*)&in[i];
    ushortx4 o;
    o[0] = f2bf(f.x); o[1] = f2bf(f.y); o[2] = f2bf(f.z); o[3] = f2bf(f.w);
    *(ushortx4*)&out[i] = o;
}

__global__ void cvt3(const float* __restrict__ i0, const float* __restrict__ i1,
                     const float* __restrict__ i2, ushort_t* __restrict__ o0,
                     ushort_t* __restrict__ o1, ushort_t* __restrict__ o2) {
    const float* in = blockIdx.y == 0 ? i0 : blockIdx.y == 1 ? i1 : i2;
    ushort_t* out = blockIdx.y == 0 ? o0 : blockIdx.y == 1 ? o1 : o2;
    cvt_body(in, out);
}

__global__ void cvt4(const float* __restrict__ i0, const float* __restrict__ i1,
                     const float* __restrict__ i2, const float* __restrict__ i3,
                     ushort_t* __restrict__ o0, ushort_t* __restrict__ o1,
                     ushort_t* __restrict__ o2, ushort_t* __restrict__ o3) {
    const float* in = blockIdx.y == 0 ? i0 : blockIdx.y == 1 ? i1
                     : blockIdx.y == 2 ? i2 : i3;
    ushort_t* out = blockIdx.y == 0 ? o0 : blockIdx.y == 1 ? o1
                   : blockIdx.y == 2 ? o2 : o3;
    cvt_body(in, out);
}

// ---------------- GEMM core: acc[m][n] = sum_k A[m,k] * B[n,k] ----------------
// 128x128 tile, BK=32, double-buffered LDS: stage tile t+1 before computing
// tile t; one __syncthreads (vmcnt0+lgkm0 drain) per K-step.
__device__ __forceinline__ void gemm_core(
    const ushort_t* __restrict__ Ab, const ushort_t* __restrict__ Bb,
    floatx4 acc[4][4], ushort_t (*As)[128][32], ushort_t (*Bs)[128][32], int tid)
{
    const int wv = tid >> 6, lane = tid & 63;
    const int quad = lane >> 4, lid = lane & 15;
    const int wm = wv & 1, wn = wv >> 1;
    const int r0 = lane >> 2, c0 = (lane & 3) * 8;

#pragma unroll
    for (int i = 0; i < 4; ++i)
#pragma unroll
        for (int j = 0; j < 4; ++j) acc[i][j] = fzero();

    // prologue: stage k0=0 into buffer 0
#pragma unroll
    for (int s = 0; s < 2; ++s) {
        int seg = wv * 2 + s;
        dma16(&Ab[(size_t)(seg * 16 + r0) * DD + c0], &As[0][seg * 16][0]);
        dma16(&Bb[(size_t)(seg * 16 + r0) * DD + c0], &Bs[0][seg * 16][0]);
    }
    __syncthreads();

    int cur = 0;
    for (int k0 = 0; k0 < DD; k0 += 32) {
        int nxt = cur ^ 1;
        if (k0 + 32 < DD) {
#pragma unroll
            for (int s = 0; s < 2; ++s) {
                int seg = wv * 2 + s;
                dma16(&Ab[(size_t)(seg * 16 + r0) * DD + k0 + 32 + c0], &As[nxt][seg * 16][0]);
                dma16(&Bb[(size_t)(seg * 16 + r0) * DD + k0 + 32 + c0], &Bs[nxt][seg * 16][0]);
            }
        }
        bf16x8 af[4], bfr[4];
#pragma unroll
        for (int mt = 0; mt < 4; ++mt) af[mt] = ldb(&As[cur][wm * 64 + mt * 16 + lid][quad * 8]);
#pragma unroll
        for (int nt = 0; nt < 4; ++nt) bfr[nt] = ldb(&Bs[cur][wn * 64 + nt * 16 + lid][quad * 8]);
#pragma unroll
        for (int mt = 0; mt < 4; ++mt)
#pragma unroll
            for (int nt = 0; nt < 4; ++nt)
                acc[mt][nt] = mfma32(af[mt], bfr[nt], acc[mt][nt]);
        __syncthreads();   // drains this iter's prefetch (vmcnt0) + ds reads
        cur = nxt;
    }
}

// ---------------- fused QKV projection ----------------
// flat grid 1536, XCD swizzle: xcd f&7 owns 192 consecutive logical blocks =
// by-range of 8 (all 24 bx) -> A-slices fetched once per XCD. logical =
// by*24+bx; bx>>3 selects {query,key,value}. Q: (B,H,S,DH) pre-scaled by
// 0.125*log2e. K: (B,H,S,DH). V: (B,H,DH,S) = V^T with mask folded in (masked
// key s -> 0). Epilogues: per-wave LDS transpose -> 16B coalesced stores.
__global__ __launch_bounds__(256) void gemm_qkv(
    const ushort_t* __restrict__ Qa, const ushort_t* __restrict__ Ka,
    const ushort_t* __restrict__ Va, const ushort_t* __restrict__ Wqkv,
    const int* __restrict__ maskg,
    ushort_t* __restrict__ Qp, ushort_t* __restrict__ Kp, ushort_t* __restrict__ Vtp)
{
    __shared__ ushort_t As[2][128][32];
    __shared__ ushort_t Bs[2][128][32];
    __shared__ ushort_t Ts[4][16][72];   // per-wave epilogue transpose buffer

    const int tid = threadIdx.x;
    const int f = blockIdx.x;
    const int logical = (f & 7) * 192 + (f >> 3);
    const int by = logical / 24;
    const int bxx = logical % 24;
    const int which = bxx >> 3;
    const int m0 = by * 128;
    const int n0 = bxx * 128;
    const ushort_t* Ab = (which == 0 ? Qa : which == 1 ? Ka : Va) + (size_t)m0 * DD;
    const ushort_t* Bb = Wqkv + (size_t)n0 * DD;

    floatx4 acc[4][4];
    gemm_core(Ab, Bb, acc, As, Bs, tid);

    const int wv = tid >> 6, lane = tid & 63;
    const int quad = lane >> 4, lid = lane & 15;
    const int wm = wv & 1, wn = wv >> 1;
    const int b = m0 >> 11;                 // batch uniform per block
    const int sbase = (m0 & 2047) + wm * 64;
    const int nl0 = n0 - which * 1024 + wn * 64;   // local n base of this wave
    const int sl = lane >> 2, cl = (lane & 3) * 16;

    if (which == 2) {
        // V^T: (B,H,DH,S), masked. Per nt: pack 4 s-consecutive vals -> b64 LDS,
        // read back dh-rows of 16 s-contiguous -> dwordx4 stores.
        const int* maskb = maskg + b * SS;
#pragma unroll
        for (int nt = 0; nt < 4; ++nt) {
#pragma unroll
            for (int mt = 0; mt < 4; ++mt) {
                int sp = sbase + mt * 16 + quad * 4;
                int4 mv = *(const int4*)&maskb[sp];
                ushortx4 o;
                o[0] = mv.x ? (ushort_t)0 : f2bf(acc[mt][nt][0]);
                o[1] = mv.y ? (ushort_t)0 : f2bf(acc[mt][nt][1]);
                o[2] = mv.z ? (ushort_t)0 : f2bf(acc[mt][nt][2]);
                o[3] = mv.w ? (ushort_t)0 : f2bf(acc[mt][nt][3]);
                *(ushortx4*)&Ts[wv][lid][mt * 16 + quad * 4] = o;
            }
            ushortx8 w0 = *(const ushortx8*)&Ts[wv][sl][cl];
            ushortx8 w1 = *(const ushortx8*)&Ts[wv][sl][cl + 8];
            int nl = nl0 + nt * 16 + sl;
            int h = nl >> 6, dh = nl & 63;
            size_t base = (((size_t)b * HH + h) * DH + dh) * SS + sbase + cl;
            *(ushortx8*)&Vtp[base] = w0;
            *(ushortx8*)&Vtp[base + 8] = w1;
        }
    } else {
        // Q/K: (B,H,S,DH). Per mt: scatter 16 b16 into LDS s-major tile, read
        // back s-rows of 16 dh-contiguous -> dwordx4 stores.
        ushort_t* P = which ? Kp : Qp;
        const float scl = which ? 1.0f : 0.125f * 1.4426950408889634f;
        const int h = nl0 >> 6;
#pragma unroll
        for (int mt = 0; mt < 4; ++mt) {
#pragma unroll
            for (int nt = 0; nt < 4; ++nt)
#pragma unroll
                for (int r = 0; r < 4; ++r)
                    Ts[wv][quad * 4 + r][nt * 16 + lid] = f2bf(acc[mt][nt][r] * scl);
            ushortx8 w0 = *(const ushortx8*)&Ts[wv][sl][cl];
            ushortx8 w1 = *(const ushortx8*)&Ts[wv][sl][cl + 8];
            int s = sbase + mt * 16 + sl;
            size_t base = (((size_t)b * HH + h) * SS + s) * DH + (nl0 & 63) + cl;
            *(ushortx8*)&P[base] = w0;
            *(ushortx8*)&P[base + 8] = w1;
        }
    }
}

// ---------------- final projection: out = Cx @ Wo^T, f32 out ----------------
// flat grid 512, XCD swizzle: xcd owns by-range of 8 (all 8 bx).
__global__ __launch_bounds__(256) void gemm_o(
    const ushort_t* __restrict__ Cx, const ushort_t* __restrict__ Wo,
    float* __restrict__ Out)
{
    __shared__ ushort_t As[2][128][32];
    __shared__ ushort_t Bs[2][128][32];
    const int tid = threadIdx.x;
    const int f = blockIdx.x;
    const int logical = (f & 7) * 64 + (f >> 3);
    const int by = logical >> 3, bx = logical & 7;
    const int m0 = by * 128;
    const int n0 = bx * 128;

    floatx4 acc[4][4];
    gemm_core(Cx + (size_t)m0 * DD, Wo + (size_t)n0 * DD, acc, As, Bs, tid);

    const int wv = tid >> 6, lane = tid & 63;
    const int quad = lane >> 4, lid = lane & 15;
    const int wm = wv & 1, wn = wv >> 1;
#pragma unroll
    for (int mt = 0; mt < 4; ++mt)
#pragma unroll
        for (int nt = 0; nt < 4; ++nt)
#pragma unroll
            for (int r = 0; r < 4; ++r) {
                int m = m0 + wm * 64 + mt * 16 + quad * 4 + r;
                int n = n0 + wn * 64 + nt * 16 + lid;
                Out[(size_t)m * DD + n] = acc[mt][nt][r];
            }
}

// ---------------- flash attention (S^T scheme, K=32 PV via key-row permute) ----
// flat grid 2048, XCD swizzle: xcd=id&7 owns 8 bh (K/V L2-resident).
// Per wave: 16 queries (q=lid). S^T = K·Q^T with key rows permuted in LDS:
// physical key p = 32kk+8quad+4h+r stored at row 32kk+16h+4quad+r. After the
// S^T MFMAs for mt-pair (2kk,2kk+1), lane (quad,lid) holds P[q=lid] for
// physical keys kk*32+quad*8+{0..7} == the exact K=32 A-fragment -> PV and the
// denominator (ones-vector fmb) run as full-rate mfma32. K/V staged by
// global_load_lds (linear LDS dest, 16B-XOR pre-swizzled global source);
// reads XOR the same (row&7)<<3 -> conflict-free ds_read_b128.
// Double-buffered: stage tile kc+1 before computing tile kc.
__global__ __launch_bounds__(256) void attn_kernel(
    const ushort_t* __restrict__ Qg, const ushort_t* __restrict__ Kg,
    const ushort_t* __restrict__ Vtg, const int* __restrict__ maskg,
    ushort_t* __restrict__ Ctx)
{
    __shared__ ushort_t Ks[2][64 * 64];    // [buf][perm key row][dh ^ swz]  16 KB
    __shared__ ushort_t Vts[2][64 * 64];   // [buf][dh][key ^ swz] (pre-masked) 16 KB
    __shared__ ushort_t fmb[SS];           // bf16 1.0/0.0 per key, all 2048  4 KB

    const int flat = blockIdx.x;
    const int xcd = flat & 7;
    const int slot = flat >> 3;
    const int bh = xcd * 8 + (slot >> 5);
    const int qc = slot & 31;
    const int b = bh >> 4, h = bh & 15;
    const int tid = threadIdx.x;
    const int wv = tid >> 6, lane = tid & 63;
    const int quad = lane >> 4, lid = lane & 15;

    const ushort_t* Qb = Qg + (size_t)bh * SS * DH;
    const ushort_t* Kb = Kg + (size_t)bh * SS * DH;
    const ushort_t* Vtb = Vtg + (size_t)bh * DH * SS;
    const int* maskb = maskg + b * SS;

    // ones-vector for all 2048 keys, staged once (8 keys/thread)
    {
        const int k8 = tid * 8;
        int4 ma = *(const int4*)&maskb[k8];
        int4 mb2 = *(const int4*)&maskb[k8 + 4];
        ushortx8 fv;
        fv[0] = ma.x ? (ushort_t)0 : (ushort_t)0x3F80;
        fv[1] = ma.y ? (ushort_t)0 : (ushort_t)0x3F80;
        fv[2] = ma.z ? (ushort_t)0 : (ushort_t)0x3F80;
        fv[3] = ma.w ? (ushort_t)0 : (ushort_t)0x3F80;
        fv[4] = mb2.x ? (ushort_t)0 : (ushort_t)0x3F80;
        fv[5] = mb2.y ? (ushort_t)0 : (ushort_t)0x3F80;
        fv[6] = mb2.z ? (ushort_t)0 : (ushort_t)0x3F80;
        fv[7] = mb2.w ? (ushort_t)0 : (ushort_t)0x3F80;
        *(ushortx8*)&fmb[k8] = fv;
    }

    const int q0 = qc * 64 + wv * 16;

    bf16x8 qf0, qf1;   // B-operand: n=lid -> query q0+lid, k=dh
    {
        const int row = q0 + lid;
        qf0 = ldb(&Qb[(size_t)row * DH + quad * 8]);
        qf1 = ldb(&Qb[(size_t)row * DH + 32 + quad * 8]);
    }

    // per-lane staging source offsets (elements), computed once.
    // lane covers LDS 16B chunk idx = wv*128 + s*64 + lane: ldsrow=idx>>3,
    // chunk c16=idx&7. K source row = perm(ldsrow); col chunk = c16 ^ (row&7).
    int offK[2], offV[2];
#pragma unroll
    for (int s = 0; s < 2; ++s) {
        int idx = wv * 128 + s * 64 + lane;
        int row = idx >> 3;
        int c16 = idx & 7;
        // perm: row bits [kk h quad r] -> p bits [kk quad h r]
        int p = (row & 35) | ((row & 12) << 1) | ((row & 16) >> 2);
        int colu = (c16 ^ (row & 7)) << 3;
        offK[s] = p * DH + colu;
        offV[s] = row * SS + colu;
    }

    floatx4 Oacc[4];
    floatx4 Osum = fzero();
#pragma unroll
    for (int i = 0; i < 4; ++i) Oacc[i] = fzero();

    const int swz = (lid & 7) << 3;

    // prologue: stage kc=0 into buffer 0
    dma16(Kb + offK[0], &Ks[0][(wv * 2 + 0) * 512]);
    dma16(Kb + offK[1], &Ks[0][(wv * 2 + 1) * 512]);
    dma16(Vtb + offV[0], &Vts[0][(wv * 2 + 0) * 512]);
    dma16(Vtb + offV[1], &Vts[0][(wv * 2 + 1) * 512]);
    __syncthreads();

    const ushort_t* Kc = Kb + 64 * DH;   // next-tile pointers
    const ushort_t* Vc = Vtb + 64;
    int cur = 0;

    for (int kc = 0; kc < SS / 64; ++kc) {
        int nxt = cur ^ 1;
        if (kc + 1 < SS / 64) {
            dma16(Kc + offK[0], &Ks[nxt][(wv * 2 + 0) * 512]);
            dma16(Kc + offK[1], &Ks[nxt][(wv * 2 + 1) * 512]);
            dma16(Vc + offV[0], &Vts[nxt][(wv * 2 + 0) * 512]);
            dma16(Vc + offV[1], &Vts[nxt][(wv * 2 + 1) * 512]);
            Kc += 64 * DH;
            Vc += 64;
        }

        // S^T = K·Q^T on permuted key rows: lane (quad,lid) gets q=lid and
        // LDS rows mt*16+quad*4+r  ==  physical keys (mt>>1)*32+quad*8+4*(mt&1)+r
        floatx4 st[4];
#pragma unroll
        for (int mt = 0; mt < 4; ++mt) {
            const int rb = (mt * 16 + lid) * 64;
            bf16x8 kf0 = ldb(&Ks[cur][rb + ((quad * 8) ^ swz)]);
            bf16x8 kf1 = ldb(&Ks[cur][rb + ((32 + quad * 8) ^ swz)]);
            st[mt] = mfma32(kf1, qf1, mfma32(kf0, qf0, fzero()));
        }

        // per 32-key block: exp2 in place -> full K=32 A-fragment, PV + denom
#pragma unroll
        for (int kk = 0; kk < 2; ++kk) {
            bf16x8 pa;
#pragma unroll
            for (int r = 0; r < 4; ++r) {
                pa[r]     = (__bf16)__builtin_amdgcn_exp2f(st[2 * kk][r]);
                pa[r + 4] = (__bf16)__builtin_amdgcn_exp2f(st[2 * kk + 1][r]);
            }
            bf16x8 fm = ldb(&fmb[kc * 64 + kk * 32 + quad * 8]);
            Osum = mfma32(pa, fm, Osum);
#pragma unroll
            for (int nt = 0; nt < 4; ++nt) {
                bf16x8 vb = ldb(&Vts[cur][(nt * 16 + lid) * 64 + ((kk * 32 + quad * 8) ^ swz)]);
                Oacc[nt] = mfma32(pa, vb, Oacc[nt]);
            }
        }
        __syncthreads();   // drains prefetch (vmcnt0) + this tile's ds reads
        cur = nxt;
    }

    // Osum[r] = row sum for q = q0+quad*4+r (identical in every column/lane-lid)
    float inv[4];
#pragma unroll
    for (int r = 0; r < 4; ++r) inv[r] = 1.0f / Osum[r];

#pragma unroll
    for (int nt = 0; nt < 4; ++nt) {
#pragma unroll
        for (int r = 0; r < 4; ++r) {
            int s = q0 + quad * 4 + r;
            int dh = nt * 16 + lid;
            Ctx[(((size_t)b * SS + s) * HH + h) * DH + dh] = f2bf(Oacc[nt][r] * inv[r]);
        }
    }
}

// ---------------- launch ----------------
extern "C" void kernel_launch(void* const* d_in, const int* in_sizes, int n_in,
                              void* d_out, int out_size, void* d_ws, size_t ws_size,
                              hipStream_t stream) {
    const float* q  = (const float*)d_in[0];
    const float* k  = (const float*)d_in[1];
    const float* v  = (const float*)d_in[2];
    const int*   mask = (const int*)d_in[3];
    const float* Wq = (const float*)d_in[4];
    const float* Wk = (const float*)d_in[5];
    const float* Wv = (const float*)d_in[6];
    const float* Wo = (const float*)d_in[7];
    float* out = (float*)d_out;

    char* ws = (char*)d_ws;
    const size_t MB = 1024 * 1024;
    ushort_t* Qin  = (ushort_t*)(ws + 0 * MB);    // 16 MB each
    ushort_t* Kin  = (ushort_t*)(ws + 16 * MB);
    ushort_t* Vin  = (ushort_t*)(ws + 32 * MB);
    ushort_t* Qp   = (ushort_t*)(ws + 48 * MB);
    ushort_t* Kp   = (ushort_t*)(ws + 64 * MB);
    ushort_t* Vtp  = (ushort_t*)(ws + 80 * MB);
    ushort_t* Wqkv = (ushort_t*)(ws + 96 * MB);   // 6 MB
    ushort_t* Wob  = (ushort_t*)(ws + 102 * MB);  // 2 MB
    ushort_t* Cx   = Qin;                         // Qin dead after gemm_qkv

    const int INEL = BB * SS * DD;   // 8.4M
    const int WN = DD * DD;          // 1M
    cvt3<<<dim3(INEL / 1024, 3), 256, 0, stream>>>(q, k, v, Qin, Kin, Vin);
    cvt4<<<dim3(WN / 1024, 4), 256, 0, stream>>>(Wq, Wk, Wv, Wo,
                                                 Wqkv, Wqkv + WN, Wqkv + 2 * WN, Wob);

    gemm_qkv<<<dim3(1536), 256, 0, stream>>>(Qin, Kin, Vin, Wqkv, mask, Qp, Kp, Vtp);
    attn_kernel<<<dim3(2048), 256, 0, stream>>>(Qp, Kp, Vtp, mask, Cx);
    gemm_o<<<dim3(512), 256, 0, stream>>>(Cx, Wob, out);
}

// Round 4
// 340.221 us; speedup vs baseline: 1.2199x; 1.0126x over previous
//
#include <hip/hip_runtime.h>

// MultiHeadAttention: B=4, S=2048, D=1024, H=16, DH=64
// out = ((softmax(mask(QK^T/8)) V) merged) @ Wo^T
// bf16 MFMA, f32 accum. No-max softmax (Q pre-scaled by 0.125*log2e).
// This round: attn waves widened to 32 queries (two 16-q groups) -> K/V/fmb
// LDS reads amortized 2x (kernel was LDS-read-BW-bound: 4.7 GB @ 69 TB/s).
// Grid 1024 blocks (64 bh x 16 q-chunks of 128). GEMMs unchanged
// (2-phase dbuf + XCD swizzle). Resubmit of round-3 (infra failure), with
// the launch_bounds occupancy floor dropped so VGPR floats (no spill risk).

#define BB 4
#define SS 2048
#define DD 1024
#define HH 16
#define DH 64

typedef __bf16 bf16x8 __attribute__((ext_vector_type(8)));
typedef float floatx4 __attribute__((ext_vector_type(4)));
typedef unsigned short ushortx8 __attribute__((ext_vector_type(8)));
typedef unsigned short ushortx4 __attribute__((ext_vector_type(4)));
typedef unsigned short ushort_t;

__device__ __forceinline__ unsigned short f2bf(float f) {
    unsigned u = __builtin_bit_cast(unsigned, f);
    u += 0x7FFFu + ((u >> 16) & 1u);   // RNE
    return (unsigned short)(u >> 16);
}

__device__ __forceinline__ bf16x8 ldb(const ushort_t* p) {
    return __builtin_bit_cast(bf16x8, *(const ushortx8*)p);
}

// async global->LDS, 16B per lane; lds dest must be wave-uniform base + lane*16
__device__ __forceinline__ void dma16(const ushort_t* g, ushort_t* l) {
    __builtin_amdgcn_global_load_lds(
        (const __attribute__((address_space(1))) unsigned int*)g,
        (__attribute__((address_space(3))) unsigned int*)l, 16, 0, 0);
}

__device__ __forceinline__ floatx4 mfma32(bf16x8 a, bf16x8 b, floatx4 c) {
    return __builtin_amdgcn_mfma_f32_16x16x32_bf16(a, b, c, 0, 0, 0);
}

__device__ __forceinline__ floatx4 fzero() {
    floatx4 z = {0.f, 0.f, 0.f, 0.f};
    return z;
}

// ---------------- f32 -> bf16 converts (merged dispatches) ----------------
__device__ __forceinline__ void cvt_body(const float* __restrict__ in,
                                         ushort_t* __restrict__ out) {
    int i = (blockIdx.x * blockDim.x + threadIdx.x) * 4;
    float4 f = *(const float4*)&in[i];
    ushortx4 o;
    o[0] = f2bf(f.x); o[1] = f2bf(f.y); o[2] = f2bf(f.z); o[3] = f2bf(f.w);
    *(ushortx4*)&out[i] = o;
}

__global__ void cvt3(const float* __restrict__ i0, const float* __restrict__ i1,
                     const float* __restrict__ i2, ushort_t* __restrict__ o0,
                     ushort_t* __restrict__ o1, ushort_t* __restrict__ o2) {
    const float* in = blockIdx.y == 0 ? i0 : blockIdx.y == 1 ? i1 : i2;
    ushort_t* out = blockIdx.y == 0 ? o0 : blockIdx.y == 1 ? o1 : o2;
    cvt_body(in, out);
}

__global__ void cvt4(const float* __restrict__ i0, const float* __restrict__ i1,
                     const float* __restrict__ i2, const float* __restrict__ i3,
                     ushort_t* __restrict__ o0, ushort_t* __restrict__ o1,
                     ushort_t* __restrict__ o2, ushort_t* __restrict__ o3) {
    const float* in = blockIdx.y == 0 ? i0 : blockIdx.y == 1 ? i1
                     : blockIdx.y == 2 ? i2 : i3;
    ushort_t* out = blockIdx.y == 0 ? o0 : blockIdx.y == 1 ? o1
                   : blockIdx.y == 2 ? o2 : o3;
    cvt_body(in, out);
}

// ---------------- GEMM core: acc[m][n] = sum_k A[m,k] * B[n,k] ----------------
// 128x128 tile, BK=32, double-buffered LDS: stage tile t+1 before computing
// tile t; one __syncthreads (vmcnt0+lgkm0 drain) per K-step.
__device__ __forceinline__ void gemm_core(
    const ushort_t* __restrict__ Ab, const ushort_t* __restrict__ Bb,
    floatx4 acc[4][4], ushort_t (*As)[128][32], ushort_t (*Bs)[128][32], int tid)
{
    const int wv = tid >> 6, lane = tid & 63;
    const int quad = lane >> 4, lid = lane & 15;
    const int wm = wv & 1, wn = wv >> 1;
    const int r0 = lane >> 2, c0 = (lane & 3) * 8;

#pragma unroll
    for (int i = 0; i < 4; ++i)
#pragma unroll
        for (int j = 0; j < 4; ++j) acc[i][j] = fzero();

    // prologue: stage k0=0 into buffer 0
#pragma unroll
    for (int s = 0; s < 2; ++s) {
        int seg = wv * 2 + s;
        dma16(&Ab[(size_t)(seg * 16 + r0) * DD + c0], &As[0][seg * 16][0]);
        dma16(&Bb[(size_t)(seg * 16 + r0) * DD + c0], &Bs[0][seg * 16][0]);
    }
    __syncthreads();

    int cur = 0;
    for (int k0 = 0; k0 < DD; k0 += 32) {
        int nxt = cur ^ 1;
        if (k0 + 32 < DD) {
#pragma unroll
            for (int s = 0; s < 2; ++s) {
                int seg = wv * 2 + s;
                dma16(&Ab[(size_t)(seg * 16 + r0) * DD + k0 + 32 + c0], &As[nxt][seg * 16][0]);
                dma16(&Bb[(size_t)(seg * 16 + r0) * DD + k0 + 32 + c0], &Bs[nxt][seg * 16][0]);
            }
        }
        bf16x8 af[4], bfr[4];
#pragma unroll
        for (int mt = 0; mt < 4; ++mt) af[mt] = ldb(&As[cur][wm * 64 + mt * 16 + lid][quad * 8]);
#pragma unroll
        for (int nt = 0; nt < 4; ++nt) bfr[nt] = ldb(&Bs[cur][wn * 64 + nt * 16 + lid][quad * 8]);
#pragma unroll
        for (int mt = 0; mt < 4; ++mt)
#pragma unroll
            for (int nt = 0; nt < 4; ++nt)
                acc[mt][nt] = mfma32(af[mt], bfr[nt], acc[mt][nt]);
        __syncthreads();   // drains this iter's prefetch (vmcnt0) + ds reads
        cur = nxt;
    }
}

// ---------------- fused QKV projection ----------------
// flat grid 1536, XCD swizzle: xcd f&7 owns 192 consecutive logical blocks =
// by-range of 8 (all 24 bx) -> A-slices fetched once per XCD. logical =
// by*24+bx; bx>>3 selects {query,key,value}. Q: (B,H,S,DH) pre-scaled by
// 0.125*log2e. K: (B,H,S,DH). V: (B,H,DH,S) = V^T with mask folded in (masked
// key s -> 0). Epilogues: per-wave LDS transpose -> 16B coalesced stores.
__global__ __launch_bounds__(256) void gemm_qkv(
    const ushort_t* __restrict__ Qa, const ushort_t* __restrict__ Ka,
    const ushort_t* __restrict__ Va, const ushort_t* __restrict__ Wqkv,
    const int* __restrict__ maskg,
    ushort_t* __restrict__ Qp, ushort_t* __restrict__ Kp, ushort_t* __restrict__ Vtp)
{
    __shared__ ushort_t As[2][128][32];
    __shared__ ushort_t Bs[2][128][32];
    __shared__ ushort_t Ts[4][16][72];   // per-wave epilogue transpose buffer

    const int tid = threadIdx.x;
    const int f = blockIdx.x;
    const int logical = (f & 7) * 192 + (f >> 3);
    const int by = logical / 24;
    const int bxx = logical % 24;
    const int which = bxx >> 3;
    const int m0 = by * 128;
    const int n0 = bxx * 128;
    const ushort_t* Ab = (which == 0 ? Qa : which == 1 ? Ka : Va) + (size_t)m0 * DD;
    const ushort_t* Bb = Wqkv + (size_t)n0 * DD;

    floatx4 acc[4][4];
    gemm_core(Ab, Bb, acc, As, Bs, tid);

    const int wv = tid >> 6, lane = tid & 63;
    const int quad = lane >> 4, lid = lane & 15;
    const int wm = wv & 1, wn = wv >> 1;
    const int b = m0 >> 11;                 // batch uniform per block
    const int sbase = (m0 & 2047) + wm * 64;
    const int nl0 = n0 - which * 1024 + wn * 64;   // local n base of this wave
    const int sl = lane >> 2, cl = (lane & 3) * 16;

    if (which == 2) {
        // V^T: (B,H,DH,S), masked. Per nt: pack 4 s-consecutive vals -> b64 LDS,
        // read back dh-rows of 16 s-contiguous -> dwordx4 stores.
        const int* maskb = maskg + b * SS;
#pragma unroll
        for (int nt = 0; nt < 4; ++nt) {
#pragma unroll
            for (int mt = 0; mt < 4; ++mt) {
                int sp = sbase + mt * 16 + quad * 4;
                int4 mv = *(const int4*)&maskb[sp];
                ushortx4 o;
                o[0] = mv.x ? (ushort_t)0 : f2bf(acc[mt][nt][0]);
                o[1] = mv.y ? (ushort_t)0 : f2bf(acc[mt][nt][1]);
                o[2] = mv.z ? (ushort_t)0 : f2bf(acc[mt][nt][2]);
                o[3] = mv.w ? (ushort_t)0 : f2bf(acc[mt][nt][3]);
                *(ushortx4*)&Ts[wv][lid][mt * 16 + quad * 4] = o;
            }
            ushortx8 w0 = *(const ushortx8*)&Ts[wv][sl][cl];
            ushortx8 w1 = *(const ushortx8*)&Ts[wv][sl][cl + 8];
            int nl = nl0 + nt * 16 + sl;
            int h = nl >> 6, dh = nl & 63;
            size_t base = (((size_t)b * HH + h) * DH + dh) * SS + sbase + cl;
            *(ushortx8*)&Vtp[base] = w0;
            *(ushortx8*)&Vtp[base + 8] = w1;
        }
    } else {
        // Q/K: (B,H,S,DH). Per mt: scatter 16 b16 into LDS s-major tile, read
        // back s-rows of 16 dh-contiguous -> dwordx4 stores.
        ushort_t* P = which ? Kp : Qp;
        const float scl = which ? 1.0f : 0.125f * 1.4426950408889634f;
        const int h = nl0 >> 6;
#pragma unroll
        for (int mt = 0; mt < 4; ++mt) {
#pragma unroll
            for (int nt = 0; nt < 4; ++nt)
#pragma unroll
                for (int r = 0; r < 4; ++r)
                    Ts[wv][quad * 4 + r][nt * 16 + lid] = f2bf(acc[mt][nt][r] * scl);
            ushortx8 w0 = *(const ushortx8*)&Ts[wv][sl][cl];
            ushortx8 w1 = *(const ushortx8*)&Ts[wv][sl][cl + 8];
            int s = sbase + mt * 16 + sl;
            size_t base = (((size_t)b * HH + h) * SS + s) * DH + (nl0 & 63) + cl;
            *(ushortx8*)&P[base] = w0;
            *(ushortx8*)&P[base + 8] = w1;
        }
    }
}

// ---------------- final projection: out = Cx @ Wo^T, f32 out ----------------
// flat grid 512, XCD swizzle: xcd owns by-range of 8 (all 8 bx).
__global__ __launch_bounds__(256) void gemm_o(
    const ushort_t* __restrict__ Cx, const ushort_t* __restrict__ Wo,
    float* __restrict__ Out)
{
    __shared__ ushort_t As[2][128][32];
    __shared__ ushort_t Bs[2][128][32];
    const int tid = threadIdx.x;
    const int f = blockIdx.x;
    const int logical = (f & 7) * 64 + (f >> 3);
    const int by = logical >> 3, bx = logical & 7;
    const int m0 = by * 128;
    const int n0 = bx * 128;

    floatx4 acc[4][4];
    gemm_core(Cx + (size_t)m0 * DD, Wo + (size_t)n0 * DD, acc, As, Bs, tid);

    const int wv = tid >> 6, lane = tid & 63;
    const int quad = lane >> 4, lid = lane & 15;
    const int wm = wv & 1, wn = wv >> 1;
#pragma unroll
    for (int mt = 0; mt < 4; ++mt)
#pragma unroll
        for (int nt = 0; nt < 4; ++nt)
#pragma unroll
            for (int r = 0; r < 4; ++r) {
                int m = m0 + wm * 64 + mt * 16 + quad * 4 + r;
                int n = n0 + wn * 64 + nt * 16 + lid;
                Out[(size_t)m * DD + n] = acc[mt][nt][r];
            }
}

// ---------------- flash attention (S^T scheme, K=32 PV, 32 q/wave) ----------
// flat grid 1024, XCD swizzle: xcd=id&7 owns 8 bh (K/V L2-resident).
// Per wave: 32 queries = two 16-q groups sharing all K/V/fmb LDS reads.
// S^T = K·Q^T with key rows PERMUTED in LDS (p = 32kk+8quad+4h+r stored at
// row 32kk+16h+4quad+r) so the S^T output of an mt-pair is in-register in
// exact K=32 A-fragment layout -> PV and denominator run as full-rate mfma32
// with zero cross-lane moves. K/V staged by global_load_lds (linear LDS dest,
// 16B-XOR pre-swizzled global source); reads XOR the same (row&7)<<3 ->
// conflict-free ds_read_b128. Double-buffered (stage kc+1 before compute kc).
__global__ __launch_bounds__(256) void attn_kernel(
    const ushort_t* __restrict__ Qg, const ushort_t* __restrict__ Kg,
    const ushort_t* __restrict__ Vtg, const int* __restrict__ maskg,
    ushort_t* __restrict__ Ctx)
{
    __shared__ ushort_t Ks[2][64 * 64];    // [buf][perm key row][dh ^ swz]  16 KB
    __shared__ ushort_t Vts[2][64 * 64];   // [buf][dh][key ^ swz] (pre-masked) 16 KB
    __shared__ ushort_t fmb[SS];           // bf16 1.0/0.0 per key, all 2048  4 KB

    const int flat = blockIdx.x;
    const int xcd = flat & 7;
    const int slot = flat >> 3;            // 0..127
    const int bh = xcd * 8 + (slot >> 4);
    const int qc = slot & 15;
    const int b = bh >> 4, h = bh & 15;
    const int tid = threadIdx.x;
    const int wv = tid >> 6, lane = tid & 63;
    const int quad = lane >> 4, lid = lane & 15;

    const ushort_t* Qb = Qg + (size_t)bh * SS * DH;
    const ushort_t* Kb = Kg + (size_t)bh * SS * DH;
    const ushort_t* Vtb = Vtg + (size_t)bh * DH * SS;
    const int* maskb = maskg + b * SS;

    // ones-vector for all 2048 keys, staged once (8 keys/thread)
    {
        const int k8 = tid * 8;
        int4 ma = *(const int4*)&maskb[k8];
        int4 mb2 = *(const int4*)&maskb[k8 + 4];
        ushortx8 fv;
        fv[0] = ma.x ? (ushort_t)0 : (ushort_t)0x3F80;
        fv[1] = ma.y ? (ushort_t)0 : (ushort_t)0x3F80;
        fv[2] = ma.z ? (ushort_t)0 : (ushort_t)0x3F80;
        fv[3] = ma.w ? (ushort_t)0 : (ushort_t)0x3F80;
        fv[4] = mb2.x ? (ushort_t)0 : (ushort_t)0x3F80;
        fv[5] = mb2.y ? (ushort_t)0 : (ushort_t)0x3F80;
        fv[6] = mb2.z ? (ushort_t)0 : (ushort_t)0x3F80;
        fv[7] = mb2.w ? (ushort_t)0 : (ushort_t)0x3F80;
        *(ushortx8*)&fmb[k8] = fv;
    }

    const int qbase = qc * 128 + wv * 32;

    bf16x8 qf[2][2];   // [group][dh half]; B-operand: n=lid -> query, k=dh
#pragma unroll
    for (int g = 0; g < 2; ++g) {
        const int row = qbase + g * 16 + lid;
        qf[g][0] = ldb(&Qb[(size_t)row * DH + quad * 8]);
        qf[g][1] = ldb(&Qb[(size_t)row * DH + 32 + quad * 8]);
    }

    // per-lane staging source offsets (elements), computed once.
    // lane covers LDS 16B chunk idx = wv*128 + s*64 + lane: ldsrow=idx>>3,
    // chunk c16=idx&7. K source row = perm(ldsrow); col chunk = c16 ^ (row&7).
    int offK[2], offV[2];
#pragma unroll
    for (int s = 0; s < 2; ++s) {
        int idx = wv * 128 + s * 64 + lane;
        int row = idx >> 3;
        int c16 = idx & 7;
        // perm: row bits [kk h quad r] -> p bits [kk quad h r]
        int p = (row & 35) | ((row & 12) << 1) | ((row & 16) >> 2);
        int colu = (c16 ^ (row & 7)) << 3;
        offK[s] = p * DH + colu;
        offV[s] = row * SS + colu;
    }

    floatx4 Oacc[2][4];
    floatx4 Osum[2];
#pragma unroll
    for (int g = 0; g < 2; ++g) {
        Osum[g] = fzero();
#pragma unroll
        for (int i = 0; i < 4; ++i) Oacc[g][i] = fzero();
    }

    const int swz = (lid & 7) << 3;

    // prologue: stage kc=0 into buffer 0
    dma16(Kb + offK[0], &Ks[0][(wv * 2 + 0) * 512]);
    dma16(Kb + offK[1], &Ks[0][(wv * 2 + 1) * 512]);
    dma16(Vtb + offV[0], &Vts[0][(wv * 2 + 0) * 512]);
    dma16(Vtb + offV[1], &Vts[0][(wv * 2 + 1) * 512]);
    __syncthreads();

    const ushort_t* Kc = Kb + 64 * DH;   // next-tile pointers
    const ushort_t* Vc = Vtb + 64;
    int cur = 0;

    for (int kc = 0; kc < SS / 64; ++kc) {
        int nxt = cur ^ 1;
        if (kc + 1 < SS / 64) {
            dma16(Kc + offK[0], &Ks[nxt][(wv * 2 + 0) * 512]);
            dma16(Kc + offK[1], &Ks[nxt][(wv * 2 + 1) * 512]);
            dma16(Vc + offV[0], &Vts[nxt][(wv * 2 + 0) * 512]);
            dma16(Vc + offV[1], &Vts[nxt][(wv * 2 + 1) * 512]);
            Kc += 64 * DH;
            Vc += 64;
        }

        // per 32-key block kk: S^T for both q-groups (K reads shared), exp2,
        // then PV + denominator (V/fmb reads shared across groups).
#pragma unroll
        for (int kk = 0; kk < 2; ++kk) {
            floatx4 sA[2], sB[2];
#pragma unroll
            for (int m2 = 0; m2 < 2; ++m2) {
                const int mt = kk * 2 + m2;
                const int rb = (mt * 16 + lid) * 64;
                bf16x8 kf0 = ldb(&Ks[cur][rb + ((quad * 8) ^ swz)]);
                bf16x8 kf1 = ldb(&Ks[cur][rb + ((32 + quad * 8) ^ swz)]);
                sA[m2] = mfma32(kf1, qf[0][1], mfma32(kf0, qf[0][0], fzero()));
                sB[m2] = mfma32(kf1, qf[1][1], mfma32(kf0, qf[1][0], fzero()));
            }
            bf16x8 pa, pb;
#pragma unroll
            for (int r = 0; r < 4; ++r) {
                pa[r]     = (__bf16)__builtin_amdgcn_exp2f(sA[0][r]);
                pa[r + 4] = (__bf16)__builtin_amdgcn_exp2f(sA[1][r]);
                pb[r]     = (__bf16)__builtin_amdgcn_exp2f(sB[0][r]);
                pb[r + 4] = (__bf16)__builtin_amdgcn_exp2f(sB[1][r]);
            }
            bf16x8 fm = ldb(&fmb[kc * 64 + kk * 32 + quad * 8]);
            Osum[0] = mfma32(pa, fm, Osum[0]);
            Osum[1] = mfma32(pb, fm, Osum[1]);
#pragma unroll
            for (int nt = 0; nt < 4; ++nt) {
                bf16x8 vb = ldb(&Vts[cur][(nt * 16 + lid) * 64 + ((kk * 32 + quad * 8) ^ swz)]);
                Oacc[0][nt] = mfma32(pa, vb, Oacc[0][nt]);
                Oacc[1][nt] = mfma32(pb, vb, Oacc[1][nt]);
            }
        }
        __syncthreads();   // drains prefetch (vmcnt0) + this tile's ds reads
        cur = nxt;
    }

    // Osum[g][r] = row sum for q = qbase+g*16+quad*4+r (same in every lane col)
#pragma unroll
    for (int g = 0; g < 2; ++g) {
        float inv[4];
#pragma unroll
        for (int r = 0; r < 4; ++r) inv[r] = 1.0f / Osum[g][r];
#pragma unroll
        for (int nt = 0; nt < 4; ++nt) {
#pragma unroll
            for (int r = 0; r < 4; ++r) {
                int s = qbase + g * 16 + quad * 4 + r;
                int dh = nt * 16 + lid;
                Ctx[(((size_t)b * SS + s) * HH + h) * DH + dh] = f2bf(Oacc[g][nt][r] * inv[r]);
            }
        }
    }
}

// ---------------- launch ----------------
extern "C" void kernel_launch(void* const* d_in, const int* in_sizes, int n_in,
                              void* d_out, int out_size, void* d_ws, size_t ws_size,
                              hipStream_t stream) {
    const float* q  = (const float*)d_in[0];
    const float* k  = (const float*)d_in[1];
    const float* v  = (const float*)d_in[2];
    const int*   mask = (const int*)d_in[3];
    const float* Wq = (const float*)d_in[4];
    const float* Wk = (const float*)d_in[5];
    const float* Wv = (const float*)d_in[6];
    const float* Wo = (const float*)d_in[7];
    float* out = (float*)d_out;

    char* ws = (char*)d_ws;
    const size_t MB = 1024 * 1024;
    ushort_t* Qin  = (ushort_t*)(ws + 0 * MB);    // 16 MB each
    ushort_t* Kin  = (ushort_t*)(ws + 16 * MB);
    ushort_t* Vin  = (ushort_t*)(ws + 32 * MB);
    ushort_t* Qp   = (ushort_t*)(ws + 48 * MB);
    ushort_t* Kp   = (ushort_t*)(ws + 64 * MB);
    ushort_t* Vtp  = (ushort_t*)(ws + 80 * MB);
    ushort_t* Wqkv = (ushort_t*)(ws + 96 * MB);   // 6 MB
    ushort_t* Wob  = (ushort_t*)(ws + 102 * MB);  // 2 MB
    ushort_t* Cx   = Qin;                         // Qin dead after gemm_qkv

    const int INEL = BB * SS * DD;   // 8.4M
    const int WN = DD * DD;          // 1M
    cvt3<<<dim3(INEL / 1024, 3), 256, 0, stream>>>(q, k, v, Qin, Kin, Vin);
    cvt4<<<dim3(WN / 1024, 4), 256, 0, stream>>>(Wq, Wk, Wv, Wo,
                                                 Wqkv, Wqkv + WN, Wqkv + 2 * WN, Wob);

    gemm_qkv<<<dim3(1536), 256, 0, stream>>>(Qin, Kin, Vin, Wqkv, mask, Qp, Kp, Vtp);
    attn_kernel<<<dim3(1024), 256, 0, stream>>>(Qp, Kp, Vtp, mask, Cx);
    gemm_o<<<dim3(512), 256, 0, stream>>>(Cx, Wob, out);
}

// Round 5
// 328.922 us; speedup vs baseline: 1.2619x; 1.0344x over previous
//
#include <hip/hip_runtime.h>

// MultiHeadAttention: B=4, S=2048, D=1024, H=16, DH=64
// out = ((softmax(mask(QK^T/8)) V) merged) @ Wo^T
// bf16 MFMA, f32 accum. No-max softmax (Q pre-scaled by 0.125*log2e).
// This round (occupancy): (1) attn drops the fmb LDS buffer entirely -- mask
// folded into K rows (zeroed in gemm_qkv) so masked P==1; denominator uses a
// constant-ones B-operand and subtracts per-batch n_masked (wave shuffle-
// reduce). LDS 36.9->32 KB = 5 blocks/CU. (2) gemm_qkv aliases its epilogue
// transpose buffer Ts onto As (dead until after K-loop) -> 41.2->32 KB =
// 3->5 blocks/CU on a latency-bound kernel.

#define BB 4
#define SS 2048
#define DD 1024
#define HH 16
#define DH 64

typedef __bf16 bf16x8 __attribute__((ext_vector_type(8)));
typedef float floatx4 __attribute__((ext_vector_type(4)));
typedef unsigned short ushortx8 __attribute__((ext_vector_type(8)));
typedef unsigned short ushortx4 __attribute__((ext_vector_type(4)));
typedef unsigned short ushort_t;

__device__ __forceinline__ unsigned short f2bf(float f) {
    unsigned u = __builtin_bit_cast(unsigned, f);
    u += 0x7FFFu + ((u >> 16) & 1u);   // RNE
    return (unsigned short)(u >> 16);
}

__device__ __forceinline__ bf16x8 ldb(const ushort_t* p) {
    return __builtin_bit_cast(bf16x8, *(const ushortx8*)p);
}

// async global->LDS, 16B per lane; lds dest must be wave-uniform base + lane*16
__device__ __forceinline__ void dma16(const ushort_t* g, ushort_t* l) {
    __builtin_amdgcn_global_load_lds(
        (const __attribute__((address_space(1))) unsigned int*)g,
        (__attribute__((address_space(3))) unsigned int*)l, 16, 0, 0);
}

__device__ __forceinline__ floatx4 mfma32(bf16x8 a, bf16x8 b, floatx4 c) {
    return __builtin_amdgcn_mfma_f32_16x16x32_bf16(a, b, c, 0, 0, 0);
}

__device__ __forceinline__ floatx4 fzero() {
    floatx4 z = {0.f, 0.f, 0.f, 0.f};
    return z;
}

// ---------------- f32 -> bf16 converts (merged dispatches) ----------------
__device__ __forceinline__ void cvt_body(const float* __restrict__ in,
                                         ushort_t* __restrict__ out) {
    int i = (blockIdx.x * blockDim.x + threadIdx.x) * 4;
    float4 f = *(const float4*)&in[i];
    ushortx4 o;
    o[0] = f2bf(f.x); o[1] = f2bf(f.y); o[2] = f2bf(f.z); o[3] = f2bf(f.w);
    *(ushortx4*)&out[i] = o;
}

__global__ void cvt3(const float* __restrict__ i0, const float* __restrict__ i1,
                     const float* __restrict__ i2, ushort_t* __restrict__ o0,
                     ushort_t* __restrict__ o1, ushort_t* __restrict__ o2) {
    const float* in = blockIdx.y == 0 ? i0 : blockIdx.y == 1 ? i1 : i2;
    ushort_t* out = blockIdx.y == 0 ? o0 : blockIdx.y == 1 ? o1 : o2;
    cvt_body(in, out);
}

__global__ void cvt4(const float* __restrict__ i0, const float* __restrict__ i1,
                     const float* __restrict__ i2, const float* __restrict__ i3,
                     ushort_t* __restrict__ o0, ushort_t* __restrict__ o1,
                     ushort_t* __restrict__ o2, ushort_t* __restrict__ o3) {
    const float* in = blockIdx.y == 0 ? i0 : blockIdx.y == 1 ? i1
                     : blockIdx.y == 2 ? i2 : i3;
    ushort_t* out = blockIdx.y == 0 ? o0 : blockIdx.y == 1 ? o1
                   : blockIdx.y == 2 ? o2 : o3;
    cvt_body(in, out);
}

// ---------------- GEMM core: acc[m][n] = sum_k A[m,k] * B[n,k] ----------------
// 128x128 tile, BK=32, double-buffered LDS: stage tile t+1 before computing
// tile t; one __syncthreads (vmcnt0+lgkm0 drain) per K-step.
__device__ __forceinline__ void gemm_core(
    const ushort_t* __restrict__ Ab, const ushort_t* __restrict__ Bb,
    floatx4 acc[4][4], ushort_t (*As)[128][32], ushort_t (*Bs)[128][32], int tid)
{
    const int wv = tid >> 6, lane = tid & 63;
    const int quad = lane >> 4, lid = lane & 15;
    const int wm = wv & 1, wn = wv >> 1;
    const int r0 = lane >> 2, c0 = (lane & 3) * 8;

#pragma unroll
    for (int i = 0; i < 4; ++i)
#pragma unroll
        for (int j = 0; j < 4; ++j) acc[i][j] = fzero();

    // prologue: stage k0=0 into buffer 0
#pragma unroll
    for (int s = 0; s < 2; ++s) {
        int seg = wv * 2 + s;
        dma16(&Ab[(size_t)(seg * 16 + r0) * DD + c0], &As[0][seg * 16][0]);
        dma16(&Bb[(size_t)(seg * 16 + r0) * DD + c0], &Bs[0][seg * 16][0]);
    }
    __syncthreads();

    int cur = 0;
    for (int k0 = 0; k0 < DD; k0 += 32) {
        int nxt = cur ^ 1;
        if (k0 + 32 < DD) {
#pragma unroll
            for (int s = 0; s < 2; ++s) {
                int seg = wv * 2 + s;
                dma16(&Ab[(size_t)(seg * 16 + r0) * DD + k0 + 32 + c0], &As[nxt][seg * 16][0]);
                dma16(&Bb[(size_t)(seg * 16 + r0) * DD + k0 + 32 + c0], &Bs[nxt][seg * 16][0]);
            }
        }
        bf16x8 af[4], bfr[4];
#pragma unroll
        for (int mt = 0; mt < 4; ++mt) af[mt] = ldb(&As[cur][wm * 64 + mt * 16 + lid][quad * 8]);
#pragma unroll
        for (int nt = 0; nt < 4; ++nt) bfr[nt] = ldb(&Bs[cur][wn * 64 + nt * 16 + lid][quad * 8]);
#pragma unroll
        for (int mt = 0; mt < 4; ++mt)
#pragma unroll
            for (int nt = 0; nt < 4; ++nt)
                acc[mt][nt] = mfma32(af[mt], bfr[nt], acc[mt][nt]);
        __syncthreads();   // drains this iter's prefetch (vmcnt0) + ds reads
        cur = nxt;
    }
}

// ---------------- fused QKV projection ----------------
// flat grid 1536, XCD swizzle: xcd f&7 owns 192 consecutive logical blocks =
// by-range of 8 (all 24 bx) -> A-slices fetched once per XCD. logical =
// by*24+bx; bx>>3 selects {query,key,value}. Q: (B,H,S,DH) pre-scaled by
// 0.125*log2e. K: (B,H,S,DH), masked rows ZEROED (so attn's P=exp2(0)=1 for
// masked keys; denominator corrected by n_masked). V: (B,H,DH,S) = V^T with
// mask folded in. Epilogue transpose buffer Ts ALIASES As (dead after the
// K-loop's final barrier) -> LDS 32 KB -> 5 blocks/CU.
__global__ __launch_bounds__(256) void gemm_qkv(
    const ushort_t* __restrict__ Qa, const ushort_t* __restrict__ Ka,
    const ushort_t* __restrict__ Va, const ushort_t* __restrict__ Wqkv,
    const int* __restrict__ maskg,
    ushort_t* __restrict__ Qp, ushort_t* __restrict__ Kp, ushort_t* __restrict__ Vtp)
{
    __shared__ ushort_t As[2][128][32];
    __shared__ ushort_t Bs[2][128][32];
    // per-wave epilogue transpose buffer, aliased onto As (16384 B >= 9216 B);
    // safe: last As read precedes the K-loop's final __syncthreads.
    ushort_t (*Ts)[16][72] = reinterpret_cast<ushort_t (*)[16][72]>(&As[0][0][0]);

    const int tid = threadIdx.x;
    const int f = blockIdx.x;
    const int logical = (f & 7) * 192 + (f >> 3);
    const int by = logical / 24;
    const int bxx = logical % 24;
    const int which = bxx >> 3;
    const int m0 = by * 128;
    const int n0 = bxx * 128;
    const ushort_t* Ab = (which == 0 ? Qa : which == 1 ? Ka : Va) + (size_t)m0 * DD;
    const ushort_t* Bb = Wqkv + (size_t)n0 * DD;

    floatx4 acc[4][4];
    gemm_core(Ab, Bb, acc, As, Bs, tid);

    const int wv = tid >> 6, lane = tid & 63;
    const int quad = lane >> 4, lid = lane & 15;
    const int wm = wv & 1, wn = wv >> 1;
    const int b = m0 >> 11;                 // batch uniform per block
    const int sbase = (m0 & 2047) + wm * 64;
    const int nl0 = n0 - which * 1024 + wn * 64;   // local n base of this wave
    const int sl = lane >> 2, cl = (lane & 3) * 16;
    const int* maskb = maskg + b * SS;

    if (which == 2) {
        // V^T: (B,H,DH,S), masked. Per nt: pack 4 s-consecutive vals -> b64 LDS,
        // read back dh-rows of 16 s-contiguous -> dwordx4 stores.
#pragma unroll
        for (int nt = 0; nt < 4; ++nt) {
#pragma unroll
            for (int mt = 0; mt < 4; ++mt) {
                int sp = sbase + mt * 16 + quad * 4;
                int4 mv = *(const int4*)&maskb[sp];
                ushortx4 o;
                o[0] = mv.x ? (ushort_t)0 : f2bf(acc[mt][nt][0]);
                o[1] = mv.y ? (ushort_t)0 : f2bf(acc[mt][nt][1]);
                o[2] = mv.z ? (ushort_t)0 : f2bf(acc[mt][nt][2]);
                o[3] = mv.w ? (ushort_t)0 : f2bf(acc[mt][nt][3]);
                *(ushortx4*)&Ts[wv][lid][mt * 16 + quad * 4] = o;
            }
            ushortx8 w0 = *(const ushortx8*)&Ts[wv][sl][cl];
            ushortx8 w1 = *(const ushortx8*)&Ts[wv][sl][cl + 8];
            int nl = nl0 + nt * 16 + sl;
            int h = nl >> 6, dh = nl & 63;
            size_t base = (((size_t)b * HH + h) * DH + dh) * SS + sbase + cl;
            *(ushortx8*)&Vtp[base] = w0;
            *(ushortx8*)&Vtp[base + 8] = w1;
        }
    } else {
        // Q/K: (B,H,S,DH). K rows for masked keys zeroed. Per mt: scatter 16
        // b16 into LDS s-major tile, read back s-rows -> dwordx4 stores.
        ushort_t* P = which ? Kp : Qp;
        const float scl = which ? 1.0f : 0.125f * 1.4426950408889634f;
        const int h = nl0 >> 6;
#pragma unroll
        for (int mt = 0; mt < 4; ++mt) {
            int mvr[4] = {0, 0, 0, 0};
            if (which) {
                int4 mv = *(const int4*)&maskb[sbase + mt * 16 + quad * 4];
                mvr[0] = mv.x; mvr[1] = mv.y; mvr[2] = mv.z; mvr[3] = mv.w;
            }
#pragma unroll
            for (int nt = 0; nt < 4; ++nt)
#pragma unroll
                for (int r = 0; r < 4; ++r)
                    Ts[wv][quad * 4 + r][nt * 16 + lid] =
                        mvr[r] ? (ushort_t)0 : f2bf(acc[mt][nt][r] * scl);
            ushortx8 w0 = *(const ushortx8*)&Ts[wv][sl][cl];
            ushortx8 w1 = *(const ushortx8*)&Ts[wv][sl][cl + 8];
            int s = sbase + mt * 16 + sl;
            size_t base = (((size_t)b * HH + h) * SS + s) * DH + (nl0 & 63) + cl;
            *(ushortx8*)&P[base] = w0;
            *(ushortx8*)&P[base + 8] = w1;
        }
    }
}

// ---------------- final projection: out = Cx @ Wo^T, f32 out ----------------
// flat grid 512, XCD swizzle: xcd owns by-range of 8 (all 8 bx).
__global__ __launch_bounds__(256) void gemm_o(
    const ushort_t* __restrict__ Cx, const ushort_t* __restrict__ Wo,
    float* __restrict__ Out)
{
    __shared__ ushort_t As[2][128][32];
    __shared__ ushort_t Bs[2][128][32];
    const int tid = threadIdx.x;
    const int f = blockIdx.x;
    const int logical = (f & 7) * 64 + (f >> 3);
    const int by = logical >> 3, bx = logical & 7;
    const int m0 = by * 128;
    const int n0 = bx * 128;

    floatx4 acc[4][4];
    gemm_core(Cx + (size_t)m0 * DD, Wo + (size_t)n0 * DD, acc, As, Bs, tid);

    const int wv = tid >> 6, lane = tid & 63;
    const int quad = lane >> 4, lid = lane & 15;
    const int wm = wv & 1, wn = wv >> 1;
#pragma unroll
    for (int mt = 0; mt < 4; ++mt)
#pragma unroll
        for (int nt = 0; nt < 4; ++nt)
#pragma unroll
            for (int r = 0; r < 4; ++r) {
                int m = m0 + wm * 64 + mt * 16 + quad * 4 + r;
                int n = n0 + wn * 64 + nt * 16 + lid;
                Out[(size_t)m * DD + n] = acc[mt][nt][r];
            }
}

// ---------------- flash attention (S^T scheme, K=32 PV, 32 q/wave) ----------
// flat grid 1024, XCD swizzle: xcd=id&7 owns 8 bh (K/V L2-resident).
// Per wave: 32 queries = two 16-q groups sharing all K/V LDS reads.
// S^T = K·Q^T with key rows PERMUTED in LDS (p = 32kk+8quad+4h+r stored at
// row 32kk+16h+4quad+r) so the S^T output of an mt-pair is in-register in
// exact K=32 A-fragment layout -> PV and denominator run as full-rate mfma32.
// Mask handling: masked K rows are zero (S=0 -> P=1); masked V^T cols zero;
// denominator = mfma(P, ones) - n_masked (per-batch scalar, wave-reduced).
// LDS exactly 32 KB -> 5 blocks/CU. Double-buffered staging via
// global_load_lds with 16B-XOR pre-swizzled source; conflict-free reads.
__global__ __launch_bounds__(256) void attn_kernel(
    const ushort_t* __restrict__ Qg, const ushort_t* __restrict__ Kg,
    const ushort_t* __restrict__ Vtg, const int* __restrict__ maskg,
    ushort_t* __restrict__ Ctx)
{
    __shared__ ushort_t Ks[2][64 * 64];    // [buf][perm key row][dh ^ swz]  16 KB
    __shared__ ushort_t Vts[2][64 * 64];   // [buf][dh][key ^ swz] (pre-masked) 16 KB

    const int flat = blockIdx.x;
    const int xcd = flat & 7;
    const int slot = flat >> 3;            // 0..127
    const int bh = xcd * 8 + (slot >> 4);
    const int qc = slot & 15;
    const int b = bh >> 4, h = bh & 15;
    const int tid = threadIdx.x;
    const int wv = tid >> 6, lane = tid & 63;
    const int quad = lane >> 4, lid = lane & 15;

    const ushort_t* Qb = Qg + (size_t)bh * SS * DH;
    const ushort_t* Kb = Kg + (size_t)bh * SS * DH;
    const ushort_t* Vtb = Vtg + (size_t)bh * DH * SS;
    const int* maskb = maskg + b * SS;

    // n_masked for this batch: 32 ints/lane + wave shuffle-reduce (one-time)
    int nm = 0;
    {
        const int4* m4 = (const int4*)maskb;
#pragma unroll
        for (int i = 0; i < 8; ++i) {
            int4 m = m4[lane + i * 64];
            nm += m.x + m.y + m.z + m.w;
        }
#pragma unroll
        for (int off = 32; off; off >>= 1) nm += __shfl_xor(nm, off);
    }
    const float nmf = (float)nm;

    const int qbase = qc * 128 + wv * 32;

    bf16x8 qf[2][2];   // [group][dh half]; B-operand: n=lid -> query, k=dh
#pragma unroll
    for (int g = 0; g < 2; ++g) {
        const int row = qbase + g * 16 + lid;
        qf[g][0] = ldb(&Qb[(size_t)row * DH + quad * 8]);
        qf[g][1] = ldb(&Qb[(size_t)row * DH + 32 + quad * 8]);
    }

    // constant ones B-operand for the denominator
    ushortx8 ov;
#pragma unroll
    for (int i = 0; i < 8; ++i) ov[i] = (ushort_t)0x3F80;
    const bf16x8 ones = __builtin_bit_cast(bf16x8, ov);

    // per-lane staging source offsets (elements), computed once.
    // lane covers LDS 16B chunk idx = wv*128 + s*64 + lane: ldsrow=idx>>3,
    // chunk c16=idx&7. K source row = perm(ldsrow); col chunk = c16 ^ (row&7).
    int offK[2], offV[2];
#pragma unroll
    for (int s = 0; s < 2; ++s) {
        int idx = wv * 128 + s * 64 + lane;
        int row = idx >> 3;
        int c16 = idx & 7;
        // perm: row bits [kk h quad r] -> p bits [kk quad h r]
        int p = (row & 35) | ((row & 12) << 1) | ((row & 16) >> 2);
        int colu = (c16 ^ (row & 7)) << 3;
        offK[s] = p * DH + colu;
        offV[s] = row * SS + colu;
    }

    floatx4 Oacc[2][4];
    floatx4 Osum[2];
#pragma unroll
    for (int g = 0; g < 2; ++g) {
        Osum[g] = fzero();
#pragma unroll
        for (int i = 0; i < 4; ++i) Oacc[g][i] = fzero();
    }

    const int swz = (lid & 7) << 3;

    // prologue: stage kc=0 into buffer 0
    dma16(Kb + offK[0], &Ks[0][(wv * 2 + 0) * 512]);
    dma16(Kb + offK[1], &Ks[0][(wv * 2 + 1) * 512]);
    dma16(Vtb + offV[0], &Vts[0][(wv * 2 + 0) * 512]);
    dma16(Vtb + offV[1], &Vts[0][(wv * 2 + 1) * 512]);
    __syncthreads();

    const ushort_t* Kc = Kb + 64 * DH;   // next-tile pointers
    const ushort_t* Vc = Vtb + 64;
    int cur = 0;

    for (int kc = 0; kc < SS / 64; ++kc) {
        int nxt = cur ^ 1;
        if (kc + 1 < SS / 64) {
            dma16(Kc + offK[0], &Ks[nxt][(wv * 2 + 0) * 512]);
            dma16(Kc + offK[1], &Ks[nxt][(wv * 2 + 1) * 512]);
            dma16(Vc + offV[0], &Vts[nxt][(wv * 2 + 0) * 512]);
            dma16(Vc + offV[1], &Vts[nxt][(wv * 2 + 1) * 512]);
            Kc += 64 * DH;
            Vc += 64;
        }

        // per 32-key block kk: S^T for both q-groups (K reads shared), exp2,
        // then PV + denominator (V reads shared across groups).
#pragma unroll
        for (int kk = 0; kk < 2; ++kk) {
            floatx4 sA[2], sB[2];
#pragma unroll
            for (int m2 = 0; m2 < 2; ++m2) {
                const int mt = kk * 2 + m2;
                const int rb = (mt * 16 + lid) * 64;
                bf16x8 kf0 = ldb(&Ks[cur][rb + ((quad * 8) ^ swz)]);
                bf16x8 kf1 = ldb(&Ks[cur][rb + ((32 + quad * 8) ^ swz)]);
                sA[m2] = mfma32(kf1, qf[0][1], mfma32(kf0, qf[0][0], fzero()));
                sB[m2] = mfma32(kf1, qf[1][1], mfma32(kf0, qf[1][0], fzero()));
            }
            bf16x8 pa, pb;
#pragma unroll
            for (int r = 0; r < 4; ++r) {
                pa[r]     = (__bf16)__builtin_amdgcn_exp2f(sA[0][r]);
                pa[r + 4] = (__bf16)__builtin_amdgcn_exp2f(sA[1][r]);
                pb[r]     = (__bf16)__builtin_amdgcn_exp2f(sB[0][r]);
                pb[r + 4] = (__bf16)__builtin_amdgcn_exp2f(sB[1][r]);
            }
            Osum[0] = mfma32(pa, ones, Osum[0]);
            Osum[1] = mfma32(pb, ones, Osum[1]);
#pragma unroll
            for (int nt = 0; nt < 4; ++nt) {
                bf16x8 vb = ldb(&Vts[cur][(nt * 16 + lid) * 64 + ((kk * 32 + quad * 8) ^ swz)]);
                Oacc[0][nt] = mfma32(pa, vb, Oacc[0][nt]);
                Oacc[1][nt] = mfma32(pb, vb, Oacc[1][nt]);
            }
        }
        __syncthreads();   // drains prefetch (vmcnt0) + this tile's ds reads
        cur = nxt;
    }

    // Osum[g][r] = row sum for q = qbase+g*16+quad*4+r, includes +1 per masked
    // key (P=1 there) -> subtract nmf.
#pragma unroll
    for (int g = 0; g < 2; ++g) {
        float inv[4];
#pragma unroll
        for (int r = 0; r < 4; ++r) inv[r] = 1.0f / (Osum[g][r] - nmf);
#pragma unroll
        for (int nt = 0; nt < 4; ++nt) {
#pragma unroll
            for (int r = 0; r < 4; ++r) {
                int s = qbase + g * 16 + quad * 4 + r;
                int dh = nt * 16 + lid;
                Ctx[(((size_t)b * SS + s) * HH + h) * DH + dh] = f2bf(Oacc[g][nt][r] * inv[r]);
            }
        }
    }
}

// ---------------- launch ----------------
extern "C" void kernel_launch(void* const* d_in, const int* in_sizes, int n_in,
                              void* d_out, int out_size, void* d_ws, size_t ws_size,
                              hipStream_t stream) {
    const float* q  = (const float*)d_in[0];
    const float* k  = (const float*)d_in[1];
    const float* v  = (const float*)d_in[2];
    const int*   mask = (const int*)d_in[3];
    const float* Wq = (const float*)d_in[4];
    const float* Wk = (const float*)d_in[5];
    const float* Wv = (const float*)d_in[6];
    const float* Wo = (const float*)d_in[7];
    float* out = (float*)d_out;

    char* ws = (char*)d_ws;
    const size_t MB = 1024 * 1024;
    ushort_t* Qin  = (ushort_t*)(ws + 0 * MB);    // 16 MB each
    ushort_t* Kin  = (ushort_t*)(ws + 16 * MB);
    ushort_t* Vin  = (ushort_t*)(ws + 32 * MB);
    ushort_t* Qp   = (ushort_t*)(ws + 48 * MB);
    ushort_t* Kp   = (ushort_t*)(ws + 64 * MB);
    ushort_t* Vtp  = (ushort_t*)(ws + 80 * MB);
    ushort_t* Wqkv = (ushort_t*)(ws + 96 * MB);   // 6 MB
    ushort_t* Wob  = (ushort_t*)(ws + 102 * MB);  // 2 MB
    ushort_t* Cx   = Qin;                         // Qin dead after gemm_qkv

    const int INEL = BB * SS * DD;   // 8.4M
    const int WN = DD * DD;          // 1M
    cvt3<<<dim3(INEL / 1024, 3), 256, 0, stream>>>(q, k, v, Qin, Kin, Vin);
    cvt4<<<dim3(WN / 1024, 4), 256, 0, stream>>>(Wq, Wk, Wv, Wo,
                                                 Wqkv, Wqkv + WN, Wqkv + 2 * WN, Wob);

    gemm_qkv<<<dim3(1536), 256, 0, stream>>>(Qin, Kin, Vin, Wqkv, mask, Qp, Kp, Vtp);
    attn_kernel<<<dim3(1024), 256, 0, stream>>>(Qp, Kp, Vtp, mask, Cx);
    gemm_o<<<dim3(512), 256, 0, stream>>>(Cx, Wob, out);
}